// Round 4
// baseline (172.002 us; speedup 1.0000x reference)
//
#include <hip/hip_runtime.h>
#include <hip/hip_bf16.h>

// InfoNCE loss, B=4096 D=768 N=8192, T=0.5, fp32 in, fp32 scalar out.
// R4: MX-fp8 symmetric GEMM — e4m3 quantized rows, mfma_scale 16x16x128 (unity
// scales), K=128/iter, half staging traffic. Wave-per-pair prep, wide finalize.

#define B_SZ 4096
#define D_SZ 768
#define N_SZ 8192
constexpr float INV_T = 2.0f;  // 1/temperature

typedef float f32x4 __attribute__((ext_vector_type(4)));
typedef int i32x8 __attribute__((ext_vector_type(8)));
typedef __attribute__((address_space(1))) const unsigned int gu32;
typedef __attribute__((address_space(3))) unsigned int lu32;

__device__ inline void async16(const void* g, void* l) {
    // per-lane global addr, wave-uniform LDS base; lane i lands at base + i*16.
    __builtin_amdgcn_global_load_lds((gu32*)g, (lu32*)l, 16, 0, 0);
}

__device__ inline unsigned char to_fp8(float v) {
    return (unsigned char)(__builtin_amdgcn_cvt_pk_fp8_f32(v, v, 0, false) & 0xff);
}

// ---- 1) fused prep: norms + positives + e4m3 normalized rows + rowsum zeroing.
// One wave per pair i (no block barriers).
__global__ __launch_bounds__(256) void prep_k(const float* __restrict__ h1,
                                              const float* __restrict__ h2,
                                              unsigned char* __restrict__ hn8,
                                              float* __restrict__ pos,
                                              float* __restrict__ rowsum) {
    const int i = blockIdx.x * 4 + (threadIdx.x >> 6);
    const int lane = threadIdx.x & 63;
    const float* a = h1 + (size_t)i * D_SZ;
    const float* b = h2 + (size_t)i * D_SZ;
    float av[12], bv[12];
    float sa = 0.f, sb = 0.f, dt = 0.f;
#pragma unroll
    for (int j = 0; j < 12; ++j) {
        av[j] = a[lane + j * 64];
        bv[j] = b[lane + j * 64];
        sa += av[j] * av[j];
        sb += bv[j] * bv[j];
        dt += av[j] * bv[j];
    }
#pragma unroll
    for (int m = 1; m < 64; m <<= 1) {
        sa += __shfl_xor(sa, m, 64);
        sb += __shfl_xor(sb, m, 64);
        dt += __shfl_xor(dt, m, 64);
    }
    const float n1 = fmaxf(sqrtf(sa), 1e-8f), n2 = fmaxf(sqrtf(sb), 1e-8f);
    const float i1 = 1.0f / n1, i2 = 1.0f / n2;
    unsigned char* d1 = hn8 + (size_t)i * D_SZ;
    unsigned char* d2 = hn8 + (size_t)(i + B_SZ) * D_SZ;
#pragma unroll
    for (int j = 0; j < 12; ++j) {
        d1[lane + j * 64] = to_fp8(av[j] * i1);
        d2[lane + j * 64] = to_fp8(bv[j] * i2);
    }
    if (lane == 0) {
        float p = dt * i1 * i2 * INV_T;
        pos[i] = p;
        pos[i + B_SZ] = p;
        rowsum[i] = 0.f;  // ws is re-poisoned each call; zero here
        rowsum[i + B_SZ] = 0.f;
    }
}

// ---- 2) symmetric fused sim-GEMM (MX-fp8) + exp-rowsum ----
// 128x128 tile, 4 waves, 2x8 mfma_scale 16x16x128 per wave, unity e8m0 scales.
// Unpadded LDS rows of 128 B: global_load_lds w16 lands lane l at row l>>3,
// chunk l&7. Grid: 2080 upper-triangular tile pairs (ty<=tx).
#define BM 128
#define BN 128
#define BKB 128  // fp8 bytes along K per iter

__global__ __launch_bounds__(256) void gemm_reduce_k(const unsigned char* __restrict__ hn8,
                                                     float* __restrict__ rowsum) {
    __shared__ __align__(32) unsigned char As[BM * BKB];
    __shared__ __align__(32) unsigned char Bs[BN * BKB];
    // triangular index -> (ty, tx), ty <= tx
    const int b = blockIdx.x;
    int tx = (int)((sqrtf(8.0f * (float)b + 1.0f) - 1.0f) * 0.5f);
    while ((tx + 1) * (tx + 2) / 2 <= b) ++tx;
    while (tx * (tx + 1) / 2 > b) --tx;
    const int ty = b - tx * (tx + 1) / 2;
    const int rowBase = ty * BM;
    const int colBase = tx * BN;
    const bool diagBlk = (ty == tx);

    const int tid = threadIdx.x;
    const int wave = tid >> 6;
    const int lane = tid & 63;
    const int q = lane >> 4;
    const int l16 = lane & 15;

    f32x4 acc[2][8];
#pragma unroll
    for (int mt = 0; mt < 2; ++mt)
#pragma unroll
        for (int nt = 0; nt < 8; ++nt) acc[mt][nt] = (f32x4){0.f, 0.f, 0.f, 0.f};

    // staging: wave w owns rows [w*32, w*32+32) of each tile; 4 instr x 8 rows.
    const unsigned char* gAb =
        hn8 + (size_t)(rowBase + wave * 32 + (lane >> 3)) * D_SZ + (lane & 7) * 16;
    const unsigned char* gBb =
        hn8 + (size_t)(colBase + wave * 32 + (lane >> 3)) * D_SZ + (lane & 7) * 16;
    unsigned char* lA = &As[wave * 32 * BKB];
    unsigned char* lB = &Bs[wave * 32 * BKB];

    for (int k0 = 0; k0 < D_SZ; k0 += BKB) {
        __syncthreads();
#pragma unroll
        for (int t = 0; t < 4; ++t) {
            async16(gAb + k0 + t * 8 * D_SZ, lA + t * 8 * BKB);
            async16(gBb + k0 + t * 8 * D_SZ, lB + t * 8 * BKB);
        }
        __syncthreads();

        // A-frag: lane holds A[m=l16][k=q*32+j], j in [0,32) — 32 contiguous bytes.
        i32x8 a0 = *(const i32x8*)&As[(wave * 32 + l16) * BKB + q * 32];
        i32x8 a1 = *(const i32x8*)&As[(wave * 32 + 16 + l16) * BKB + q * 32];
#pragma unroll
        for (int nt = 0; nt < 8; ++nt) {
            i32x8 bf = *(const i32x8*)&Bs[(nt * 16 + l16) * BKB + q * 32];
            acc[0][nt] = __builtin_amdgcn_mfma_scale_f32_16x16x128_f8f6f4(
                a0, bf, acc[0][nt], 0, 0, 0, 0x7F7F7F7F, 0, 0x7F7F7F7F);
            acc[1][nt] = __builtin_amdgcn_mfma_scale_f32_16x16x128_f8f6f4(
                a1, bf, acc[1][nt], 0, 0, 0, 0x7F7F7F7F, 0, 0x7F7F7F7F);
        }
    }

    // epilogue: C/D layout col=l16, row=q*4+reg (shape-determined). exp once ->
    // row sums (regs) + col sums (symmetry) for off-diag blocks.
    float rs[2][4] = {{0.f, 0.f, 0.f, 0.f}, {0.f, 0.f, 0.f, 0.f}};
#pragma unroll
    for (int nt = 0; nt < 8; ++nt) {
        float cs = 0.f;
#pragma unroll
        for (int mt = 0; mt < 2; ++mt) {
#pragma unroll
            for (int r = 0; r < 4; ++r) {
                int row = rowBase + wave * 32 + mt * 16 + q * 4 + r;
                int col = colBase + nt * 16 + l16;
                float e = __expf(acc[mt][nt][r] * INV_T);
                e = (diagBlk && row == col) ? 0.f : e;
                rs[mt][r] += e;
                cs += e;
            }
        }
        if (!diagBlk) {
            cs += __shfl_xor(cs, 16, 64);
            cs += __shfl_xor(cs, 32, 64);
            if (q == 0) atomicAdd(&rowsum[colBase + nt * 16 + l16], cs);
        }
    }
#pragma unroll
    for (int mt = 0; mt < 2; ++mt) {
#pragma unroll
        for (int r = 0; r < 4; ++r) {
            float s = rs[mt][r];
#pragma unroll
            for (int m = 1; m < 16; m <<= 1) s += __shfl_xor(s, m, 16);
            if (l16 == 0)
                atomicAdd(&rowsum[rowBase + wave * 32 + mt * 16 + q * 4 + r], s);
        }
    }
}

// ---- 3) loss = mean(log(rowsum) - pos), 1024 threads, float4 loads ----
__global__ __launch_bounds__(1024) void finalize_k(const float* __restrict__ rowsum,
                                                   const float* __restrict__ pos,
                                                   float* __restrict__ out) {
    __shared__ float red[16];
    const int t = threadIdx.x;
    const float4* rs4 = (const float4*)rowsum;
    const float4* ps4 = (const float4*)pos;
    float s = 0.f;
#pragma unroll
    for (int j = 0; j < 2; ++j) {
        float4 r = rs4[t * 2 + j];
        float4 p = ps4[t * 2 + j];
        s += (__logf(r.x) - p.x) + (__logf(r.y) - p.y) +
             (__logf(r.z) - p.z) + (__logf(r.w) - p.w);
    }
#pragma unroll
    for (int m = 1; m < 64; m <<= 1) s += __shfl_xor(s, m, 64);
    if ((t & 63) == 0) red[t >> 6] = s;
    __syncthreads();
    if (t == 0) {
        float tot = 0.f;
#pragma unroll
        for (int w = 0; w < 16; ++w) tot += red[w];
        out[0] = tot * (1.0f / (float)N_SZ);
    }
}

extern "C" void kernel_launch(void* const* d_in, const int* in_sizes, int n_in,
                              void* d_out, int out_size, void* d_ws, size_t ws_size,
                              hipStream_t stream) {
    const float* h1 = (const float*)d_in[0];
    const float* h2 = (const float*)d_in[1];
    float* out = (float*)d_out;

    char* ws = (char*)d_ws;
    unsigned char* hn8 = (unsigned char*)ws;                      // N*D = 6,291,456 B
    float* pos    = (float*)(ws + (size_t)N_SZ * D_SZ);            // 32 KB
    float* rowsum = (float*)(ws + (size_t)N_SZ * D_SZ + 32768);    // 32 KB

    prep_k<<<B_SZ / 4, 256, 0, stream>>>(h1, h2, hn8, pos, rowsum);
    const int nTiles = N_SZ / BN;                    // 64
    const int nBlocks = nTiles * (nTiles + 1) / 2;   // 2080
    gemm_reduce_k<<<nBlocks, 256, 0, stream>>>(hn8, rowsum);
    finalize_k<<<1, 1024, 0, stream>>>(rowsum, pos, out);
}